// Round 1
// baseline (156.506 us; speedup 1.0000x reference)
//
#include <hip/hip_runtime.h>
#include <math.h>

#define NMAX 4096

constexpr float RADIUS       = 0.1f;
constexpr float DT           = 1.0f / 60.0f;
constexpr float MAX_VEL      = 3.0f;               // 0.5*0.1/DT
constexpr float VISCOSITY    = 60.0f;
constexpr float DENSITY_REST = 17510.1f;
constexpr float STIFFNESS    = 2.99e-11f;
constexpr float EPS          = 1e-8f;
constexpr float SPIKY_C      = (float)(15.0 / (3.14159265358979323846 * 1e-6)); // 15/(pi*R^6)

// ---------------- predict: vel += g*dt, cap, pred = locs + dt*vel ----------------
__global__ void k_predict(const float* __restrict__ locs, const float* __restrict__ vel,
                          float* __restrict__ px, float* __restrict__ py, float* __restrict__ pz,
                          int n) {
    int i = blockIdx.x * blockDim.x + threadIdx.x;
    if (i >= n) return;
    float vx = vel[3*i+0];
    float vy = vel[3*i+1] - 9.8f * DT;
    float vz = vel[3*i+2];
    float vv = sqrtf(vx*vx + vy*vy + vz*vz);
    float s  = fminf(MAX_VEL / (vv + 1e-4f), 1.0f);
    vx *= s; vy *= s; vz *= s;
    px[i] = locs[3*i+0] + DT * vx;
    py[i] = locs[3*i+1] + DT * vy;
    pz[i] = locs[3*i+2] + DT * vz;
}

// ---------------- rho pass: lam[i] = -(sum_j w_ij - rho0)*k ----------------
__global__ __launch_bounds__(256) void k_rho(const float* __restrict__ px, const float* __restrict__ py,
                                             const float* __restrict__ pz, float* __restrict__ lam, int n) {
    __shared__ float sx[NMAX], sy[NMAX], sz[NMAX];
    for (int idx = threadIdx.x; idx < n; idx += 256) {
        sx[idx] = px[idx]; sy[idx] = py[idx]; sz[idx] = pz[idx];
    }
    __syncthreads();
    int wave = threadIdx.x >> 6, lane = threadIdx.x & 63;
    int i = blockIdx.x * 4 + wave;
    if (i >= n) return;
    float xi = sx[i], yi = sy[i], zi = sz[i];
    float rho = 0.f;
#pragma unroll 4
    for (int j = lane; j < n; j += 64) {
        float dx = xi - sx[j], dy = yi - sy[j], dz = zi - sz[j];
        float d2 = dx*dx + dy*dy + dz*dz;
        float d  = __builtin_amdgcn_sqrtf(d2 + EPS);
        float t  = RADIUS - d;
        bool  m  = (d < RADIUS) & (d2 > 1e-12f);
        rho += m ? SPIKY_C * t * t * t : 0.f;
    }
    for (int off = 32; off > 0; off >>= 1) rho += __shfl_down(rho, off);
    if (lane == 0) lam[i] = -(rho - DENSITY_REST) * STIFFNESS;
}

// ---------------- delta pass: pred_new = pred + sum_j (lam_i+lam_j)*dw/d * diff ----------------
__global__ __launch_bounds__(256) void k_delta(const float* __restrict__ px, const float* __restrict__ py,
                                               const float* __restrict__ pz, const float* __restrict__ lam,
                                               float* __restrict__ qx, float* __restrict__ qy, float* __restrict__ qz,
                                               const float* __restrict__ locs,
                                               float* __restrict__ out_pred,   // nullable: interleaved pred out
                                               float* __restrict__ vnx, float* __restrict__ vny, float* __restrict__ vnz,
                                               int n) {
    __shared__ float sx[NMAX], sy[NMAX], sz[NMAX], sl[NMAX];  // 64 KB
    for (int idx = threadIdx.x; idx < n; idx += 256) {
        sx[idx] = px[idx]; sy[idx] = py[idx]; sz[idx] = pz[idx]; sl[idx] = lam[idx];
    }
    __syncthreads();
    int wave = threadIdx.x >> 6, lane = threadIdx.x & 63;
    int i = blockIdx.x * 4 + wave;
    if (i >= n) return;
    float xi = sx[i], yi = sy[i], zi = sz[i], li = sl[i];
    float ax = 0.f, ay = 0.f, az = 0.f;
#pragma unroll 4
    for (int j = lane; j < n; j += 64) {
        float dx = xi - sx[j], dy = yi - sy[j], dz = zi - sz[j];
        float d2 = dx*dx + dy*dy + dz*dz;
        float d  = __builtin_amdgcn_sqrtf(d2 + EPS);
        float t  = RADIUS - d;
        bool  m  = (d < RADIUS) & (d2 > 1e-12f);
        float dw = -3.f * SPIKY_C * t * t;
        float coef = (li + sl[j]) * dw * __builtin_amdgcn_rcpf(d);
        coef = m ? coef : 0.f;
        ax += coef * dx; ay += coef * dy; az += coef * dz;
    }
    for (int off = 32; off > 0; off >>= 1) {
        ax += __shfl_down(ax, off);
        ay += __shfl_down(ay, off);
        az += __shfl_down(az, off);
    }
    if (lane == 0) {
        float nx_ = xi + ax, ny_ = yi + ay, nz_ = zi + az;
        qx[i] = nx_; qy[i] = ny_; qz[i] = nz_;
        if (out_pred) {
            out_pred[3*i+0] = nx_;
            out_pred[3*i+1] = ny_;
            out_pred[3*i+2] = nz_;
            // new_vel = (pred - locs)/DT
            vnx[i] = (nx_ - locs[3*i+0]) * (1.0f / DT);
            vny[i] = (ny_ - locs[3*i+1]) * (1.0f / DT);
            vnz[i] = (nz_ - locs[3*i+2]) * (1.0f / DT);
        }
    }
}

// ---------------- viscosity (XSPH): out_vel = cap(v + K*(sum w v_j - wsum v_i)) ----------------
__global__ __launch_bounds__(256) void k_visc(const float* __restrict__ px, const float* __restrict__ py,
                                              const float* __restrict__ pz,
                                              const float* __restrict__ vnx, const float* __restrict__ vny,
                                              const float* __restrict__ vnz,
                                              float* __restrict__ out, int n) {
    __shared__ float sx[NMAX], sy[NMAX], sz[NMAX];
    for (int idx = threadIdx.x; idx < n; idx += 256) {
        sx[idx] = px[idx]; sy[idx] = py[idx]; sz[idx] = pz[idx];
    }
    __syncthreads();
    int wave = threadIdx.x >> 6, lane = threadIdx.x & 63;
    int i = blockIdx.x * 4 + wave;
    if (i >= n) return;
    float xi = sx[i], yi = sy[i], zi = sz[i];
    float vix = vnx[i], viy = vny[i], viz = vnz[i];
    float wsum = 0.f, ax = 0.f, ay = 0.f, az = 0.f;
#pragma unroll 4
    for (int j = lane; j < n; j += 64) {
        float dx = xi - sx[j], dy = yi - sy[j], dz = zi - sz[j];
        float d2 = dx*dx + dy*dy + dz*dz;
        float d  = __builtin_amdgcn_sqrtf(d2 + EPS);
        float t  = RADIUS - d;
        bool  m  = (d < RADIUS) & (d2 > 1e-12f);
        float w  = m ? SPIKY_C * t * t * t : 0.f;
        wsum += w;
        ax += w * vnx[j]; ay += w * vny[j]; az += w * vnz[j];
    }
    for (int off = 32; off > 0; off >>= 1) {
        wsum += __shfl_down(wsum, off);
        ax   += __shfl_down(ax, off);
        ay   += __shfl_down(ay, off);
        az   += __shfl_down(az, off);
    }
    if (lane == 0) {
        constexpr float K = VISCOSITY * DT / DENSITY_REST;
        float nvx = vix + K * (ax - wsum * vix);
        float nvy = viy + K * (ay - wsum * viy);
        float nvz = viz + K * (az - wsum * viz);
        float vv = sqrtf(nvx*nvx + nvy*nvy + nvz*nvz);
        float s  = fminf(MAX_VEL / (vv + 1e-4f), 1.0f);
        out[3*n + 3*i + 0] = nvx * s;
        out[3*n + 3*i + 1] = nvy * s;
        out[3*n + 3*i + 2] = nvz * s;
    }
}

extern "C" void kernel_launch(void* const* d_in, const int* in_sizes, int n_in,
                              void* d_out, int out_size, void* d_ws, size_t ws_size,
                              hipStream_t stream) {
    const float* locs = (const float*)d_in[0];
    const float* vel  = (const float*)d_in[1];
    float* out = (float*)d_out;
    int n = in_sizes[0] / 3;

    float* w = (float*)d_ws;
    float* p0x = w;          float* p0y = p0x + n;  float* p0z = p0y + n;
    float* p1x = p0z + n;    float* p1y = p1x + n;  float* p1z = p1y + n;
    float* lam = p1z + n;
    float* vnx = lam + n;    float* vny = vnx + n;  float* vnz = vny + n;

    int nb = (n + 3) / 4;

    k_predict<<<(n + 255) / 256, 256, 0, stream>>>(locs, vel, p0x, p0y, p0z, n);

    // iteration 1: p0 -> p1
    k_rho<<<nb, 256, 0, stream>>>(p0x, p0y, p0z, lam, n);
    k_delta<<<nb, 256, 0, stream>>>(p0x, p0y, p0z, lam, p1x, p1y, p1z,
                                    locs, nullptr, nullptr, nullptr, nullptr, n);
    // iteration 2: p1 -> p0
    k_rho<<<nb, 256, 0, stream>>>(p1x, p1y, p1z, lam, n);
    k_delta<<<nb, 256, 0, stream>>>(p1x, p1y, p1z, lam, p0x, p0y, p0z,
                                    locs, nullptr, nullptr, nullptr, nullptr, n);
    // iteration 3: p0 -> p1, also emit pred + new_vel
    k_rho<<<nb, 256, 0, stream>>>(p0x, p0y, p0z, lam, n);
    k_delta<<<nb, 256, 0, stream>>>(p0x, p0y, p0z, lam, p1x, p1y, p1z,
                                    locs, out, vnx, vny, vnz, n);
    // XSPH viscosity on final positions
    k_visc<<<nb, 256, 0, stream>>>(p1x, p1y, p1z, vnx, vny, vnz, out, n);
}

// Round 2
// 123.852 us; speedup vs baseline: 1.2637x; 1.2637x over previous
//
#include <hip/hip_runtime.h>
#include <math.h>

#define NMAX 4096
#define N4   (NMAX/4)

// n is assumed a multiple of 8 (reference: N=4096).

constexpr float RADIUS       = 0.1f;
constexpr float DT           = 1.0f / 60.0f;
constexpr float MAX_VEL      = 3.0f;               // 0.5*0.1/DT
constexpr float VISCOSITY    = 60.0f;
constexpr float DENSITY_REST = 17510.1f;
constexpr float STIFFNESS    = 2.99e-11f;
constexpr float EPS          = 1e-8f;
constexpr float SPIKY_C      = (float)(15.0 / (3.14159265358979323846 * 1e-6)); // 15/(pi*R^6)

__device__ __forceinline__ float elem(const float4& v, int c) {
    return reinterpret_cast<const float*>(&v)[c];
}

// ---------------- predict: vel += g*dt, cap, pred = locs + dt*vel ----------------
__global__ void k_predict(const float* __restrict__ locs, const float* __restrict__ vel,
                          float* __restrict__ px, float* __restrict__ py, float* __restrict__ pz,
                          int n) {
    int i = blockIdx.x * blockDim.x + threadIdx.x;
    if (i >= n) return;
    float vx = vel[3*i+0];
    float vy = vel[3*i+1] - 9.8f * DT;
    float vz = vel[3*i+2];
    float vv = sqrtf(vx*vx + vy*vy + vz*vz);
    float s  = fminf(MAX_VEL / (vv + 1e-4f), 1.0f);
    vx *= s; vy *= s; vz *= s;
    px[i] = locs[3*i+0] + DT * vx;
    py[i] = locs[3*i+1] + DT * vy;
    pz[i] = locs[3*i+2] + DT * vz;
}

// ---------------- rho pass: Lam[i] = -3C * lam[i]  (pre-scaled for delta) ----------------
// mask-free: rho = C * (sum_j relu(R-d)^3 - t_self^3); self has dx=0 so d=sqrt(EPS) exactly.
__global__ __launch_bounds__(256) void k_rho(const float4* __restrict__ px, const float4* __restrict__ py,
                                             const float4* __restrict__ pz, float* __restrict__ Lam, int n) {
    __shared__ float4 sx[N4], sy[N4], sz[N4];   // 48 KB
    int n4 = n >> 2;
    for (int idx = threadIdx.x; idx < n4; idx += 256) {
        sx[idx] = px[idx]; sy[idx] = py[idx]; sz[idx] = pz[idx];
    }
    __syncthreads();
    const int wave = threadIdx.x >> 6, lane = threadIdx.x & 63;
    const int i0 = blockIdx.x * 8 + wave * 2;
    if (i0 >= n) return;
    const float* fx = (const float*)sx; const float* fy = (const float*)sy; const float* fz = (const float*)sz;
    const float xi0 = fx[i0],   yi0 = fy[i0],   zi0 = fz[i0];
    const float xi1 = fx[i0+1], yi1 = fy[i0+1], zi1 = fz[i0+1];
    float S0 = 0.f, S1 = 0.f;
    for (int k = lane; k < n4; k += 64) {
        float4 X = sx[k], Y = sy[k], Z = sz[k];
#pragma unroll
        for (int c = 0; c < 4; ++c) {
            float xj = elem(X,c), yj = elem(Y,c), zj = elem(Z,c);
            {
                float dx = xi0-xj, dy = yi0-yj, dz = zi0-zj;
                float d2 = fmaf(dx,dx,EPS); d2 = fmaf(dy,dy,d2); d2 = fmaf(dz,dz,d2);
                float t  = fmaxf(RADIUS - __builtin_amdgcn_sqrtf(d2), 0.f);
                S0 = fmaf(t*t, t, S0);
            }
            {
                float dx = xi1-xj, dy = yi1-yj, dz = zi1-zj;
                float d2 = fmaf(dx,dx,EPS); d2 = fmaf(dy,dy,d2); d2 = fmaf(dz,dz,d2);
                float t  = fmaxf(RADIUS - __builtin_amdgcn_sqrtf(d2), 0.f);
                S1 = fmaf(t*t, t, S1);
            }
        }
    }
    for (int off = 32; off > 0; off >>= 1) {
        S0 += __shfl_down(S0, off);
        S1 += __shfl_down(S1, off);
    }
    if (lane == 0) {
        const float ts  = RADIUS - __builtin_amdgcn_sqrtf(EPS);  // matches inner self-pair exactly
        const float TS3 = ts*ts*ts;
        const float k3  = 3.f * SPIKY_C * STIFFNESS;             // L = -3C*lam = 3C*k*(rho-rho0)
        Lam[i0]   = k3 * (SPIKY_C * (S0 - TS3) - DENSITY_REST);
        Lam[i0+1] = k3 * (SPIKY_C * (S1 - TS3) - DENSITY_REST);
    }
}

// ---------------- delta pass: pred += sum_j (L_i+L_j) * t^2 / d * diff ----------------
// self: diff=0 -> contributes 0;  d>=R: t=0 -> contributes 0.  No mask needed.
__global__ __launch_bounds__(256) void k_delta(const float4* __restrict__ px, const float4* __restrict__ py,
                                               const float4* __restrict__ pz, const float4* __restrict__ Lm,
                                               float* __restrict__ qx, float* __restrict__ qy, float* __restrict__ qz,
                                               const float* __restrict__ locs,
                                               float* __restrict__ out_pred,   // nullable
                                               float* __restrict__ vnx, float* __restrict__ vny, float* __restrict__ vnz,
                                               int n) {
    __shared__ float4 sx[N4], sy[N4], sz[N4], sl[N4];   // 64 KB
    int n4 = n >> 2;
    for (int idx = threadIdx.x; idx < n4; idx += 256) {
        sx[idx] = px[idx]; sy[idx] = py[idx]; sz[idx] = pz[idx]; sl[idx] = Lm[idx];
    }
    __syncthreads();
    const int wave = threadIdx.x >> 6, lane = threadIdx.x & 63;
    const int i0 = blockIdx.x * 8 + wave * 2;
    if (i0 >= n) return;
    const float* fx = (const float*)sx; const float* fy = (const float*)sy;
    const float* fz = (const float*)sz; const float* fl = (const float*)sl;
    const float xi0 = fx[i0],   yi0 = fy[i0],   zi0 = fz[i0],   L0 = fl[i0];
    const float xi1 = fx[i0+1], yi1 = fy[i0+1], zi1 = fz[i0+1], L1 = fl[i0+1];
    float ax0=0.f, ay0=0.f, az0=0.f, ax1=0.f, ay1=0.f, az1=0.f;
    for (int k = lane; k < n4; k += 64) {
        float4 X = sx[k], Y = sy[k], Z = sz[k], L = sl[k];
#pragma unroll
        for (int c = 0; c < 4; ++c) {
            float xj = elem(X,c), yj = elem(Y,c), zj = elem(Z,c), Lj = elem(L,c);
            {
                float dx = xi0-xj, dy = yi0-yj, dz = zi0-zj;
                float d2 = fmaf(dx,dx,EPS); d2 = fmaf(dy,dy,d2); d2 = fmaf(dz,dz,d2);
                float rinv = __builtin_amdgcn_rsqf(d2);
                float t  = fmaxf(RADIUS - d2*rinv, 0.f);
                float cf = (L0 + Lj) * (t*t) * rinv;
                ax0 = fmaf(cf, dx, ax0); ay0 = fmaf(cf, dy, ay0); az0 = fmaf(cf, dz, az0);
            }
            {
                float dx = xi1-xj, dy = yi1-yj, dz = zi1-zj;
                float d2 = fmaf(dx,dx,EPS); d2 = fmaf(dy,dy,d2); d2 = fmaf(dz,dz,d2);
                float rinv = __builtin_amdgcn_rsqf(d2);
                float t  = fmaxf(RADIUS - d2*rinv, 0.f);
                float cf = (L1 + Lj) * (t*t) * rinv;
                ax1 = fmaf(cf, dx, ax1); ay1 = fmaf(cf, dy, ay1); az1 = fmaf(cf, dz, az1);
            }
        }
    }
    for (int off = 32; off > 0; off >>= 1) {
        ax0 += __shfl_down(ax0, off); ay0 += __shfl_down(ay0, off); az0 += __shfl_down(az0, off);
        ax1 += __shfl_down(ax1, off); ay1 += __shfl_down(ay1, off); az1 += __shfl_down(az1, off);
    }
    if (lane == 0) {
#pragma unroll
        for (int u = 0; u < 2; ++u) {
            int i = i0 + u;
            float nx_ = (u ? xi1+ax1 : xi0+ax0);
            float ny_ = (u ? yi1+ay1 : yi0+ay0);
            float nz_ = (u ? zi1+az1 : zi0+az0);
            qx[i] = nx_; qy[i] = ny_; qz[i] = nz_;
            if (out_pred) {
                out_pred[3*i+0] = nx_; out_pred[3*i+1] = ny_; out_pred[3*i+2] = nz_;
                vnx[i] = (nx_ - locs[3*i+0]) * (1.0f/DT);
                vny[i] = (ny_ - locs[3*i+1]) * (1.0f/DT);
                vnz[i] = (nz_ - locs[3*i+2]) * (1.0f/DT);
            }
        }
    }
}

// ---------------- XSPH viscosity: out_vel = cap(v + K*(sum w v_j - wsum v_i)) ----------------
// self term cancels in (sum w v_j - wsum v_i); no mask needed. j staged in 2 chunks of n/2.
__global__ __launch_bounds__(256) void k_visc(const float4* __restrict__ px, const float4* __restrict__ py,
                                              const float4* __restrict__ pz,
                                              const float4* __restrict__ vx, const float4* __restrict__ vy,
                                              const float4* __restrict__ vz,
                                              float* __restrict__ out, int n) {
    __shared__ float4 sx[N4/2], sy[N4/2], sz[N4/2], svx[N4/2], svy[N4/2], svz[N4/2];  // 48 KB
    const int wave = threadIdx.x >> 6, lane = threadIdx.x & 63;
    const int i0 = blockIdx.x * 8 + wave * 2;
    const float* fpx = (const float*)px; const float* fpy = (const float*)py; const float* fpz = (const float*)pz;
    const float* fvx = (const float*)vx; const float* fvy = (const float*)vy; const float* fvz = (const float*)vz;
    const float xi0 = fpx[i0],   yi0 = fpy[i0],   zi0 = fpz[i0];
    const float xi1 = fpx[i0+1], yi1 = fpy[i0+1], zi1 = fpz[i0+1];
    const float vix0 = fvx[i0],   viy0 = fvy[i0],   viz0 = fvz[i0];
    const float vix1 = fvx[i0+1], viy1 = fvy[i0+1], viz1 = fvz[i0+1];
    float ws0=0.f, ax0=0.f, ay0=0.f, az0=0.f;
    float ws1=0.f, ax1=0.f, ay1=0.f, az1=0.f;
    const int n8 = n >> 3;  // chunk size in float4
    for (int ch = 0; ch < 2; ++ch) {
        __syncthreads();
        for (int idx = threadIdx.x; idx < n8; idx += 256) {
            sx[idx]  = px[ch*n8+idx]; sy[idx]  = py[ch*n8+idx]; sz[idx]  = pz[ch*n8+idx];
            svx[idx] = vx[ch*n8+idx]; svy[idx] = vy[ch*n8+idx]; svz[idx] = vz[ch*n8+idx];
        }
        __syncthreads();
        for (int k = lane; k < n8; k += 64) {
            float4 X = sx[k], Y = sy[k], Z = sz[k], VX = svx[k], VY = svy[k], VZ = svz[k];
#pragma unroll
            for (int c = 0; c < 4; ++c) {
                float xj = elem(X,c), yj = elem(Y,c), zj = elem(Z,c);
                float vxj = elem(VX,c), vyj = elem(VY,c), vzj = elem(VZ,c);
                {
                    float dx = xi0-xj, dy = yi0-yj, dz = zi0-zj;
                    float d2 = fmaf(dx,dx,EPS); d2 = fmaf(dy,dy,d2); d2 = fmaf(dz,dz,d2);
                    float t  = fmaxf(RADIUS - __builtin_amdgcn_sqrtf(d2), 0.f);
                    float w  = t*t*t;
                    ws0 += w;
                    ax0 = fmaf(w, vxj, ax0); ay0 = fmaf(w, vyj, ay0); az0 = fmaf(w, vzj, az0);
                }
                {
                    float dx = xi1-xj, dy = yi1-yj, dz = zi1-zj;
                    float d2 = fmaf(dx,dx,EPS); d2 = fmaf(dy,dy,d2); d2 = fmaf(dz,dz,d2);
                    float t  = fmaxf(RADIUS - __builtin_amdgcn_sqrtf(d2), 0.f);
                    float w  = t*t*t;
                    ws1 += w;
                    ax1 = fmaf(w, vxj, ax1); ay1 = fmaf(w, vyj, ay1); az1 = fmaf(w, vzj, az1);
                }
            }
        }
    }
    for (int off = 32; off > 0; off >>= 1) {
        ws0 += __shfl_down(ws0, off); ax0 += __shfl_down(ax0, off);
        ay0 += __shfl_down(ay0, off); az0 += __shfl_down(az0, off);
        ws1 += __shfl_down(ws1, off); ax1 += __shfl_down(ax1, off);
        ay1 += __shfl_down(ay1, off); az1 += __shfl_down(az1, off);
    }
    if (lane == 0 && i0 < n) {
        constexpr float K = VISCOSITY * DT / DENSITY_REST;
        const float KC = K * SPIKY_C;   // w accumulated without C; fold here
#pragma unroll
        for (int u = 0; u < 2; ++u) {
            int i = i0 + u;
            float vix = (u ? vix1 : vix0), viy = (u ? viy1 : viy0), viz = (u ? viz1 : viz0);
            float sw  = (u ? ws1 : ws0);
            float sax = (u ? ax1 : ax0), say = (u ? ay1 : ay0), saz = (u ? az1 : az0);
            float nvx = vix + KC * (sax - sw * vix);
            float nvy = viy + KC * (say - sw * viy);
            float nvz = viz + KC * (saz - sw * viz);
            float vv = sqrtf(nvx*nvx + nvy*nvy + nvz*nvz);
            float s  = fminf(MAX_VEL / (vv + 1e-4f), 1.0f);
            out[3*n + 3*i + 0] = nvx * s;
            out[3*n + 3*i + 1] = nvy * s;
            out[3*n + 3*i + 2] = nvz * s;
        }
    }
}

extern "C" void kernel_launch(void* const* d_in, const int* in_sizes, int n_in,
                              void* d_out, int out_size, void* d_ws, size_t ws_size,
                              hipStream_t stream) {
    const float* locs = (const float*)d_in[0];
    const float* vel  = (const float*)d_in[1];
    float* out = (float*)d_out;
    int n = in_sizes[0] / 3;

    float* w = (float*)d_ws;
    float* p0x = w;          float* p0y = p0x + n;  float* p0z = p0y + n;
    float* p1x = p0z + n;    float* p1y = p1x + n;  float* p1z = p1y + n;
    float* lam = p1z + n;
    float* vnx = lam + n;    float* vny = vnx + n;  float* vnz = vny + n;

    int nb = n / 8;   // 2 particles/wave, 4 waves/block

    k_predict<<<(n + 255) / 256, 256, 0, stream>>>(locs, vel, p0x, p0y, p0z, n);

    // iteration 1: p0 -> p1
    k_rho<<<nb, 256, 0, stream>>>((const float4*)p0x, (const float4*)p0y, (const float4*)p0z, lam, n);
    k_delta<<<nb, 256, 0, stream>>>((const float4*)p0x, (const float4*)p0y, (const float4*)p0z,
                                    (const float4*)lam, p1x, p1y, p1z,
                                    locs, nullptr, nullptr, nullptr, nullptr, n);
    // iteration 2: p1 -> p0
    k_rho<<<nb, 256, 0, stream>>>((const float4*)p1x, (const float4*)p1y, (const float4*)p1z, lam, n);
    k_delta<<<nb, 256, 0, stream>>>((const float4*)p1x, (const float4*)p1y, (const float4*)p1z,
                                    (const float4*)lam, p0x, p0y, p0z,
                                    locs, nullptr, nullptr, nullptr, nullptr, n);
    // iteration 3: p0 -> p1, also emit pred + new_vel
    k_rho<<<nb, 256, 0, stream>>>((const float4*)p0x, (const float4*)p0y, (const float4*)p0z, lam, n);
    k_delta<<<nb, 256, 0, stream>>>((const float4*)p0x, (const float4*)p0y, (const float4*)p0z,
                                    (const float4*)lam, p1x, p1y, p1z,
                                    locs, out, vnx, vny, vnz, n);
    // XSPH viscosity on final positions
    k_visc<<<nb, 256, 0, stream>>>((const float4*)p1x, (const float4*)p1y, (const float4*)p1z,
                                   (const float4*)vnx, (const float4*)vny, (const float4*)vnz, out, n);
}